// Round 5
// baseline (487.797 us; speedup 1.0000x reference)
//
#include <hip/hip_runtime.h>

// HGNN conv: out = degv ⊙ (H @ ((w*deg_e) ⊙ (H^T @ (degv ⊙ (x@W))))) + bias ; w = sigmoid(H^T (x V))
// N=8192, E=4096, F=512, density 2%. R16: SPARSE rewrite of the H-side products.
// H is binary, 2% dense (~671K nnz). Dense pipeline spent ~81us materializing Hbf/HTbf and
// ~190us on G2/t2t/G3/final. Now: bld_kernel builds per-node and per-edge index lists in one
// 128MB pass (ballot+wave-scan node side, atomicAdd edge side); zsum/degv become tiny
// L1-resident gathers; H^T@ and H@ become row-gather SpMMs over L2/L3-resident operands
// (dout 8MB, t2 4MB). Only dense GEMM left is x@W (EPI3: degv-row-scaled bf16).

#define N_NODES 8192
#define N_EDGES 4096
#define FT 512
#define NODE_CAP 160   // max edges per node: mean 82, sd 9 -> 8.7 sigma
#define EDGE_CAP 256   // max nodes per edge: mean 164, sd 12.7 -> 7.3 sigma

typedef short bf16x8 __attribute__((ext_vector_type(8)));
typedef float f32x4 __attribute__((ext_vector_type(4)));
typedef unsigned short u16;
typedef unsigned int u32;

__device__ __forceinline__ u16 f2b(float f) {
    union { float f; u32 u; } v; v.f = f;
    u32 r = v.u + 0x7FFFu + ((v.u >> 16) & 1u);   // RNE
    return (u16)(r >> 16);
}
__device__ __forceinline__ float b2f(u16 h) {
    union { u32 u; float f; } v; v.u = ((u32)h) << 16; return v.f;
}

// ---------------- scalar-path kernels ----------------

// xv[n] = x[n,:] . V ; xb = bf16(x) ; blocks 0..15 zero edge_cnt (4096 u32)
__global__ __launch_bounds__(256) void xv_xb_kernel(const float* __restrict__ x,
                                                    const float* __restrict__ V,
                                                    float* __restrict__ xv,
                                                    u16* __restrict__ xb,
                                                    u32* __restrict__ edge_cnt) {
    if (blockIdx.x < 16) edge_cnt[blockIdx.x * 256 + threadIdx.x] = 0u;
    int row = blockIdx.x * 4 + (threadIdx.x >> 6);
    int lane = threadIdx.x & 63;
    const float* xr = x + (size_t)row * FT + lane * 8;
    const float* vr = V + lane * 8;
    float4 a0 = *(const float4*)xr, a1 = *(const float4*)(xr + 4);
    float4 b0 = *(const float4*)vr, b1 = *(const float4*)(vr + 4);
    float acc = a0.x * b0.x + a0.y * b0.y + a0.z * b0.z + a0.w * b0.w +
                a1.x * b1.x + a1.y * b1.y + a1.z * b1.z + a1.w * b1.w;
    u16 tmp[8] = {f2b(a0.x), f2b(a0.y), f2b(a0.z), f2b(a0.w),
                  f2b(a1.x), f2b(a1.y), f2b(a1.z), f2b(a1.w)};
    *(uint4*)(xb + (size_t)row * FT + lane * 8) = *(uint4*)tmp;
#pragma unroll
    for (int off = 32; off; off >>= 1) acc += __shfl_down(acc, off);
    if (lane == 0) xv[row] = acc;
}

// Build adjacency lists from dense H in one pass. One wave per node row (16KB read).
// Node side: ballot + wave prefix-scan, no atomics. Edge side: atomicAdd append.
__global__ __launch_bounds__(256) void bld_kernel(const float* __restrict__ H,
                                                  u16* __restrict__ node_list,
                                                  u32* __restrict__ node_cnt,
                                                  u16* __restrict__ edge_list,
                                                  u32* __restrict__ edge_cnt) {
    const int n = blockIdx.x * 4 + (threadIdx.x >> 6);
    const int lane = threadIdx.x & 63;
    const float4* hrow = (const float4*)(H + (size_t)n * N_EDGES);
    u16* nl = node_list + (size_t)n * NODE_CAP;
    int base = 0;
    for (int chunk = 0; chunk < 16; chunk++) {
        float4 h = hrow[chunk * 64 + lane];
        u32 m = (h.x != 0.f ? 1u : 0u) | (h.y != 0.f ? 2u : 0u) |
                (h.z != 0.f ? 4u : 0u) | (h.w != 0.f ? 8u : 0u);
        int c = __popc(m);
        int sc = c;                         // inclusive scan over 64 lanes
#pragma unroll
        for (int off = 1; off < 64; off <<= 1) {
            int v = __shfl_up(sc, off);
            if (lane >= off) sc += v;
        }
        int ofs = base + sc - c;            // exclusive prefix
        int tot = __shfl(sc, 63);
        int e0 = chunk * 256 + lane * 4;
#pragma unroll
        for (int j = 0; j < 4; j++) {
            if (m & (1u << j)) {
                int e = e0 + j;
                if (ofs < NODE_CAP) nl[ofs] = (u16)e;
                ofs++;
                u32 pos = atomicAdd(&edge_cnt[e], 1u);
                if (pos < EDGE_CAP) edge_list[(size_t)e * EDGE_CAP + pos] = (u16)n;
            }
        }
        base += tot;
    }
    if (lane == 0) node_cnt[n] = (u32)(base < NODE_CAP ? base : NODE_CAP);
}

// Per edge: z = sum xv[members]; w = sigmoid(z); wde = w * count. One wave per edge.
__global__ __launch_bounds__(256) void zde_kernel(const u16* __restrict__ edge_list,
                                                  const u32* __restrict__ edge_cnt,
                                                  const float* __restrict__ xv,
                                                  float* __restrict__ w_out,
                                                  float* __restrict__ wde) {
    int e = blockIdx.x * 4 + (threadIdx.x >> 6);
    int lane = threadIdx.x & 63;
    int cnt = (int)edge_cnt[e]; if (cnt > EDGE_CAP) cnt = EDGE_CAP;
    const u16* el = edge_list + (size_t)e * EDGE_CAP;
    float z = 0.f;
    for (int i = lane; i < cnt; i += 64) z += xv[el[i]];
#pragma unroll
    for (int off = 32; off; off >>= 1) z += __shfl_down(z, off);
    if (lane == 0) {
        float wv = 1.f / (1.f + expf(-z));
        w_out[e] = wv;
        wde[e] = wv * (float)cnt;
    }
}

// Per node: degv[n] = sum w[member edges]. One wave per node (w is 16KB, L1-resident).
__global__ __launch_bounds__(256) void degv2_kernel(const u16* __restrict__ node_list,
                                                    const u32* __restrict__ node_cnt,
                                                    const float* __restrict__ w,
                                                    float* __restrict__ degv) {
    int n = blockIdx.x * 4 + (threadIdx.x >> 6);
    int lane = threadIdx.x & 63;
    int cnt = (int)node_cnt[n];
    const u16* nl = node_list + (size_t)n * NODE_CAP;
    float acc = 0.f;
    for (int i = lane; i < cnt; i += 64) acc += w[nl[i]];
#pragma unroll
    for (int off = 32; off; off >>= 1) acc += __shfl_down(acc, off);
    if (lane == 0) degv[n] = acc;
}

// W (FT,FT) fp32 -> WT (FT,FT) bf16 transposed
__global__ void wt_kernel(const float* __restrict__ src, u16* __restrict__ dst) {
    __shared__ float tile[32][33];
    int tx = threadIdx.x, ty = threadIdx.y;
    int c = blockIdx.x * 32 + tx;
    int r0 = blockIdx.y * 32;
#pragma unroll
    for (int i = 0; i < 4; i++)
        tile[ty + i * 8][tx] = src[(size_t)(r0 + ty + i * 8) * FT + c];
    __syncthreads();
#pragma unroll
    for (int i = 0; i < 4; i++)
        dst[(size_t)(blockIdx.x * 32 + ty + i * 8) * FT + r0 + tx] = f2b(tile[tx][ty + i * 8]);
}

// SpMM1: t2[e][f] = f2b(wde[e] * sum_{n in edge e} dout[n][f]).  Block per edge, 2 feats/thread.
__global__ __launch_bounds__(256) void spmm1_kernel(const u16* __restrict__ edge_list,
                                                    const u32* __restrict__ edge_cnt,
                                                    const u16* __restrict__ dout,
                                                    const float* __restrict__ wde,
                                                    u16* __restrict__ t2) {
    const int e = blockIdx.x;
    const int tid = threadIdx.x;
    int cnt = (int)edge_cnt[e]; if (cnt > EDGE_CAP) cnt = EDGE_CAP;
    const u16* el = edge_list + (size_t)e * EDGE_CAP;
    float a0 = 0.f, a1 = 0.f;
    int i = 0;
    for (; i + 4 <= cnt; i += 4) {          // 4 rows in flight (MLP)
        int n0 = el[i + 0], n1 = el[i + 1], n2 = el[i + 2], n3 = el[i + 3];
        u32 v0 = *(const u32*)(dout + (size_t)n0 * FT + tid * 2);
        u32 v1 = *(const u32*)(dout + (size_t)n1 * FT + tid * 2);
        u32 v2 = *(const u32*)(dout + (size_t)n2 * FT + tid * 2);
        u32 v3 = *(const u32*)(dout + (size_t)n3 * FT + tid * 2);
        a0 += b2f((u16)(v0 & 0xFFFFu)); a1 += b2f((u16)(v0 >> 16));
        a0 += b2f((u16)(v1 & 0xFFFFu)); a1 += b2f((u16)(v1 >> 16));
        a0 += b2f((u16)(v2 & 0xFFFFu)); a1 += b2f((u16)(v2 >> 16));
        a0 += b2f((u16)(v3 & 0xFFFFu)); a1 += b2f((u16)(v3 >> 16));
    }
    for (; i < cnt; i++) {
        u32 v = *(const u32*)(dout + (size_t)el[i] * FT + tid * 2);
        a0 += b2f((u16)(v & 0xFFFFu)); a1 += b2f((u16)(v >> 16));
    }
    float s = wde[e];
    u32 o = (u32)f2b(s * a0) | ((u32)f2b(s * a1) << 16);
    *(u32*)(t2 + (size_t)e * FT + tid * 2) = o;
}

// SpMM2: out[n][f] = degv[n] * sum_{e in node n} t2[e][f] + bias[f].  Block per node.
__global__ __launch_bounds__(256) void spmm2_kernel(const u16* __restrict__ node_list,
                                                    const u32* __restrict__ node_cnt,
                                                    const u16* __restrict__ t2,
                                                    const float* __restrict__ degv,
                                                    const float* __restrict__ bias,
                                                    float* __restrict__ out) {
    const int n = blockIdx.x;
    const int tid = threadIdx.x;
    int cnt = (int)node_cnt[n];
    const u16* nl = node_list + (size_t)n * NODE_CAP;
    float a0 = 0.f, a1 = 0.f;
    int i = 0;
    for (; i + 4 <= cnt; i += 4) {
        int e0 = nl[i + 0], e1 = nl[i + 1], e2 = nl[i + 2], e3 = nl[i + 3];
        u32 v0 = *(const u32*)(t2 + (size_t)e0 * FT + tid * 2);
        u32 v1 = *(const u32*)(t2 + (size_t)e1 * FT + tid * 2);
        u32 v2 = *(const u32*)(t2 + (size_t)e2 * FT + tid * 2);
        u32 v3 = *(const u32*)(t2 + (size_t)e3 * FT + tid * 2);
        a0 += b2f((u16)(v0 & 0xFFFFu)); a1 += b2f((u16)(v0 >> 16));
        a0 += b2f((u16)(v1 & 0xFFFFu)); a1 += b2f((u16)(v1 >> 16));
        a0 += b2f((u16)(v2 & 0xFFFFu)); a1 += b2f((u16)(v2 >> 16));
        a0 += b2f((u16)(v3 & 0xFFFFu)); a1 += b2f((u16)(v3 >> 16));
    }
    for (; i < cnt; i++) {
        u32 v = *(const u32*)(t2 + (size_t)nl[i] * FT + tid * 2);
        a0 += b2f((u16)(v & 0xFFFFu)); a1 += b2f((u16)(v >> 16));
    }
    float dv = degv[n];
    float2 o;
    o.x = dv * a0 + bias[tid * 2 + 0];
    o.y = dv * a1 + bias[tid * 2 + 1];
    *(float2*)(out + (size_t)n * FT + tid * 2) = o;
}

// ---------------- MFMA GEMM: TBK=64, full-DMA + rotate-by-row swizzle ----------------
// Tile (MT*32) x (NT*32), 4 waves (2x2). bf16 row-major operands, k-contiguous.
// EPI 3: bf16 store C[m*ldc+n] scaled by degv[m] (row scaling)

#define TBK 64

template <int MT, int NT, int EPI>
__global__ __launch_bounds__(256, 4)
void gemm9(const u16* __restrict__ Ap, const u16* __restrict__ Bp,
           void* __restrict__ Cp, const float* __restrict__ degv,
           int KC, int lda, int ldb, int ldc) {
    __shared__ __align__(16) u16 Alds[MT * 32 * TBK];
    __shared__ __align__(16) u16 Blds[NT * 32 * TBK];
    const int t = threadIdx.x;
    const int m0 = blockIdx.x * (MT * 32), n0 = blockIdx.y * (NT * 32);
    const int wave = t >> 6, lane = t & 63, quad = lane >> 4, lo = lane & 15;
    const int wm = (wave >> 1) * (MT * 16), wn = (wave & 1) * (NT * 16);

    f32x4 acc[MT][NT];
#pragma unroll
    for (int a = 0; a < MT; a++)
#pragma unroll
        for (int b = 0; b < NT; b++) acc[a][b] = (f32x4){0.f, 0.f, 0.f, 0.f};

    for (int kk = 0; kk < KC; kk += TBK) {
        __syncthreads();
#pragma unroll
        for (int i = 0; i < MT; i++) {            // A: MT*32 rows x 8 chunks
            int c = t + i * 256;
            int r = c >> 3;
            int j = ((c & 7) - r) & 7;
            const u16* g = Ap + (size_t)(m0 + r) * lda + kk + j * 8;
            __builtin_amdgcn_global_load_lds((const u32*)g, (u32*)(Alds + c * 8), 16, 0, 0);
        }
#pragma unroll
        for (int i = 0; i < NT; i++) {            // B: NT*32 rows x 8 chunks
            int c = t + i * 256;
            int r = c >> 3;
            int j = ((c & 7) - r) & 7;
            const u16* g = Bp + (size_t)(n0 + r) * ldb + kk + j * 8;
            __builtin_amdgcn_global_load_lds((const u32*)g, (u32*)(Blds + c * 8), 16, 0, 0);
        }
        __syncthreads();

#pragma unroll
        for (int s2 = 0; s2 < 2; s2++) {
            bf16x8 af[MT], bfr[NT];
#pragma unroll
            for (int mt = 0; mt < MT; mt++) {
                int m = wm + mt * 16 + lo;
                int s = (s2 * 4 + quad + m) & 7;
                af[mt] = *(const bf16x8*)&Alds[m * TBK + s * 8];
            }
#pragma unroll
            for (int nt = 0; nt < NT; nt++) {
                int n = wn + nt * 16 + lo;
                int s = (s2 * 4 + quad + n) & 7;
                bfr[nt] = *(const bf16x8*)&Blds[n * TBK + s * 8];
            }
#pragma unroll
            for (int mt = 0; mt < MT; mt++)
#pragma unroll
                for (int nt = 0; nt < NT; nt++)
                    acc[mt][nt] = __builtin_amdgcn_mfma_f32_16x16x32_bf16(af[mt], bfr[nt], acc[mt][nt], 0, 0, 0);
        }
    }

    // epilogue: D[row=quad*4+i][col=lo] per 16x16 tile
    if (EPI == 3) {
        u16* C = (u16*)Cp;
#pragma unroll
        for (int mt = 0; mt < MT; mt++) {
            int rb = m0 + wm + mt * 16 + quad * 4;
#pragma unroll
            for (int i = 0; i < 4; i++) {
                float dvv = degv[rb + i];
#pragma unroll
                for (int nt = 0; nt < NT; nt++)
                    C[(size_t)(rb + i) * ldc + n0 + wn + nt * 16 + lo] =
                        f2b(acc[mt][nt][i] * dvv);
            }
        }
    }
}

// ---------------- launch ----------------

extern "C" void kernel_launch(void* const* d_in, const int* in_sizes, int n_in,
                              void* d_out, int out_size, void* d_ws, size_t ws_size,
                              hipStream_t stream) {
    const float* x    = (const float*)d_in[0];
    const float* H    = (const float*)d_in[1];
    const float* W    = (const float*)d_in[2];
    const float* V    = (const float*)d_in[3];
    const float* bias = (const float*)d_in[4];
    float* out  = (float*)d_out;                       // (N, FT)
    float* wout = out + (size_t)N_NODES * FT;          // (E,)
    (void)in_sizes; (void)n_in; (void)out_size; (void)ws_size;

    char* wsb = (char*)d_ws;
    float* xv        = (float*)(wsb + 0);          //  32 KB ->    32768
    float* degv      = (float*)(wsb + 32768);      //  32 KB ->    65536
    float* wde       = (float*)(wsb + 65536);      //  16 KB ->    81920
    u32*   edge_cnt  = (u32*)  (wsb + 81920);      //  16 KB ->    98304
    u32*   node_cnt  = (u32*)  (wsb + 98304);      //  32 KB ->   131072
    u16*   edge_list = (u16*)  (wsb + 131072);     //   2 MB ->  2228224
    u16*   node_list = (u16*)  (wsb + 2228224);    // 2.5 MB ->  4849664
    u16*   WT        = (u16*)  (wsb + 4849664);    // 0.5 MB ->  5373952
    u16*   xb        = (u16*)  (wsb + 5373952);    //   8 MB -> 13762560
    u16*   dout      = (u16*)  (wsb + 13762560);   //   8 MB -> 22151168
    u16*   t2        = (u16*)  (wsb + 22151168);   //   4 MB -> 26345472

    // xv, xb, and zero edge_cnt
    xv_xb_kernel<<<N_NODES / 4, 256, 0, stream>>>(x, V, xv, xb, edge_cnt);
    // adjacency lists from dense H (single 128MB pass)
    bld_kernel<<<N_NODES / 4, 256, 0, stream>>>(H, node_list, node_cnt, edge_list, edge_cnt);
    // z -> sigmoid -> w, wde (desum == count)
    zde_kernel<<<N_EDGES / 4, 256, 0, stream>>>(edge_list, edge_cnt, xv, wout, wde);
    // degv[n] = sum w over member edges
    degv2_kernel<<<N_NODES / 4, 256, 0, stream>>>(node_list, node_cnt, wout, degv);
    // W -> WT bf16
    wt_kernel<<<dim3(16, 16), dim3(32, 8), 0, stream>>>(W, WT);
    // dout[n][f] = bf16(degv[n] * sum_fi xb[n,fi]*WT[f,fi])  (M=8192, N=512, K=512)
    gemm9<2, 4, 3><<<dim3(N_NODES / 64, FT / 128, 1), 256, 0, stream>>>(
        xb, WT, dout, degv, FT, FT, FT, FT);
    // t2[e][f] = bf16(wde[e] * sum_{n in e} dout[n][f])
    spmm1_kernel<<<N_EDGES, 256, 0, stream>>>(edge_list, edge_cnt, dout, wde, t2);
    // out[n][f] = degv[n] * sum_{e in n} t2[e][f] + bias[f]
    spmm2_kernel<<<N_NODES, 256, 0, stream>>>(node_list, node_cnt, t2, degv, bias, out);
}

// Round 6
// 360.627 us; speedup vs baseline: 1.3526x; 1.3526x over previous
//
#include <hip/hip_runtime.h>

// HGNN conv: out = degv ⊙ (H @ ((w*deg_e) ⊙ (H^T @ (degv ⊙ (x@W))))) + bias ; w = sigmoid(H^T (x V))
// N=8192, E=4096, F=512. R17: revert to R14 dense pipeline (sparse R16 lost: bld latency-
// serial 192us, scattered L3 gathers ~5.5TB/s). Deltas vs R14: (a) dispatch merges (zero
// into xv_xb, sigmoid+wt merged) 11->9 kernels; (b) prep_h5 = 128x128 tiles (4x per-thread
// ILP, 256B contiguous runs, 1/4 blocks, 1/2 atomics) targeting prep's 2.5TB/s duty cycle.
// GEMMs / t2t / final byte-identical to R14 (354us best).

#define N_NODES 8192
#define N_EDGES 4096
#define FT 512

typedef short bf16x8 __attribute__((ext_vector_type(8)));
typedef float f32x4 __attribute__((ext_vector_type(4)));
typedef unsigned short u16;
typedef unsigned int u32;

__device__ __forceinline__ u16 f2b(float f) {
    union { float f; u32 u; } v; v.f = f;
    u32 r = v.u + 0x7FFFu + ((v.u >> 16) & 1u);   // RNE
    return (u16)(r >> 16);
}
__device__ __forceinline__ float b2f(u16 h) {
    union { u32 u; float f; } v; v.u = ((u32)h) << 16; return v.f;
}

// ---------------- scalar-path kernels ----------------

// xv[n] = x[n,:] . V ; xb = bf16(x) ; blocks 0..31 zero zsum+desum (8192 f contiguous)
__global__ __launch_bounds__(256) void xv_xb_kernel(const float* __restrict__ x,
                                                    const float* __restrict__ V,
                                                    float* __restrict__ xv,
                                                    u16* __restrict__ xb,
                                                    float* __restrict__ zd) {
    if (blockIdx.x < 32) zd[blockIdx.x * 256 + threadIdx.x] = 0.f;
    int row = blockIdx.x * 4 + (threadIdx.x >> 6);
    int lane = threadIdx.x & 63;
    const float* xr = x + (size_t)row * FT + lane * 8;
    const float* vr = V + lane * 8;
    float4 a0 = *(const float4*)xr, a1 = *(const float4*)(xr + 4);
    float4 b0 = *(const float4*)vr, b1 = *(const float4*)(vr + 4);
    float acc = a0.x * b0.x + a0.y * b0.y + a0.z * b0.z + a0.w * b0.w +
                a1.x * b1.x + a1.y * b1.y + a1.z * b1.z + a1.w * b1.w;
    u16 tmp[8] = {f2b(a0.x), f2b(a0.y), f2b(a0.z), f2b(a0.w),
                  f2b(a1.x), f2b(a1.y), f2b(a1.z), f2b(a1.w)};
    *(uint4*)(xb + (size_t)row * FT + lane * 8) = *(uint4*)tmp;
#pragma unroll
    for (int off = 32; off; off >>= 1) acc += __shfl_down(acc, off);
    if (lane == 0) xv[row] = acc;
}

// Fused prep, 128(e) x 128(n) tile: Hbf = bf16(H); HTbf = Hbf^T;
// zsum[e] += sum_n H[n,e]*xv[n]; desum[e] += colsum.
// Phase 1: thread (r=t>>1, h=t&1) reads 64 contiguous e's (256B), converts to 32 packed
// u32 e-pairs, writes LDS only. Barrier. Hbf stored from regs post-barrier (256B runs).
// Phase 2: thread (e=t>>1, g=t&1) perm-transposes 64 n's (32 u32), writes 128B run,
// accumulates z/d branchlessly, pair-reduces, one atomic per (e, half-pair).
__global__ __launch_bounds__(256) void prep_h5_kernel(const float* __restrict__ H,
                                                      const float* __restrict__ xv,
                                                      u16* __restrict__ Hbf,
                                                      u16* __restrict__ HTbf,
                                                      float* __restrict__ zsum,
                                                      float* __restrict__ desum) {
    __shared__ u32 Wt[128][65];                   // Wt[n][ew] = packed e-pair (2ew, 2ew+1)
    __shared__ float xvs[128];
    const int t = threadIdx.x;
    const int e0 = blockIdx.x * 128, n0 = blockIdx.y * 128;
    if (t < 128) xvs[t] = xv[n0 + t];
    const int r = t >> 1, h = t & 1;              // phase-1 ids
    u32 o[32];
    {   // phase 1: load 64 e's, convert, LDS write only
        const float* src = H + (size_t)(n0 + r) * N_EDGES + e0 + h * 64;
#pragma unroll
        for (int j = 0; j < 16; j++) {
            float4 v = *(const float4*)(src + j * 4);
            o[2 * j]     = (v.x != 0.f ? 0x3F80u : 0u) | (v.y != 0.f ? 0x3F800000u : 0u);
            o[2 * j + 1] = (v.z != 0.f ? 0x3F80u : 0u) | (v.w != 0.f ? 0x3F800000u : 0u);
        }
#pragma unroll
        for (int k = 0; k < 32; k++) Wt[r][h * 32 + k] = o[k];
    }
    __syncthreads();
    {   // Hbf stores after the barrier (from regs): 128B contiguous per thread
        u16* hdst = Hbf + (size_t)(n0 + r) * N_EDGES + e0 + h * 64;
#pragma unroll
        for (int k = 0; k < 8; k++)
            *(uint4*)(hdst + k * 8) = *(uint4*)&o[k * 4];
    }
    {   // phase 2: transpose + colsum. thread (e = t>>1, g = t&1) handles 64 n's
        const int e = t >> 1, g = t & 1;
        const int ew = e >> 1;
        const u32 sel = (e & 1) ? 0x07060302u : 0x05040100u;
        u32 oo[32];
        float z = 0.f, d = 0.f;
#pragma unroll
        for (int j = 0; j < 32; j++) {
            int np = g * 32 + j;                  // n-pair index: n = 2np, 2np+1
            oo[j] = __builtin_amdgcn_perm(Wt[2 * np + 1][ew], Wt[2 * np][ew], sel);
            z += (oo[j] & 0xFFFFu) ? xvs[2 * np] : 0.f;
            d += (oo[j] & 0xFFFFu) ? 1.f : 0.f;
            z += (oo[j] >> 16) ? xvs[2 * np + 1] : 0.f;
            d += (oo[j] >> 16) ? 1.f : 0.f;
        }
        u16* drow = HTbf + (size_t)(e0 + e) * N_NODES + n0 + g * 64;
#pragma unroll
        for (int k = 0; k < 8; k++)
            *(uint4*)(drow + k * 8) = *(uint4*)&oo[k * 4];
        z += __shfl_down(z, 1);
        d += __shfl_down(d, 1);
        if (g == 0) {
            atomicAdd(zsum + e0 + e, z);
            atomicAdd(desum + e0 + e, d);
        }
    }
}

// Merged: blocks 0..15 = sigmoid (w, wde); blocks 16..271 = W -> WT (bf16 transpose)
__global__ __launch_bounds__(256) void sigwt_kernel(const float* __restrict__ zsum,
                                                    const float* __restrict__ desum,
                                                    float* __restrict__ w_out,
                                                    float* __restrict__ wde,
                                                    const float* __restrict__ W,
                                                    u16* __restrict__ WT) {
    __shared__ float tile[32][33];
    int bx = blockIdx.x;
    if (bx < 16) {
        int e = bx * 256 + threadIdx.x;
        float z = zsum[e];
        float wv = 1.f / (1.f + expf(-z));
        w_out[e] = wv;
        wde[e] = wv * desum[e];
    } else {
        int b = bx - 16;
        int bxx = b & 15, byy = b >> 4;
        int tx = threadIdx.x & 31, ty = threadIdx.x >> 5;
        int c = bxx * 32 + tx;
        int r0 = byy * 32;
#pragma unroll
        for (int i = 0; i < 4; i++)
            tile[ty + i * 8][tx] = W[(size_t)(r0 + ty + i * 8) * FT + c];
        __syncthreads();
#pragma unroll
        for (int i = 0; i < 4; i++)
            WT[(size_t)(bxx * 32 + ty + i * 8) * FT + r0 + tx] = f2b(tile[tx][ty + i * 8]);
    }
}

// degv[n] = Hbf[n,:] . w   (one wave per row; coalesced w loads, cndmask adds)
__global__ __launch_bounds__(256) void degv_kernel(const u16* __restrict__ Hbf,
                                                   const float* __restrict__ w,
                                                   float* __restrict__ degv) {
    int row = blockIdx.x * 4 + (threadIdx.x >> 6);
    int lane = threadIdx.x & 63;
    const uint4* hr = (const uint4*)(Hbf + (size_t)row * N_EDGES);
    float acc = 0.f;
#pragma unroll
    for (int i = 0; i < 8; i++) {
        int idx = i * 64 + lane;
        uint4 h = hr[idx];
        const float* w8 = w + idx * 8;
        float4 wa = *(const float4*)w8, wb = *(const float4*)(w8 + 4);
        acc += (h.x & 0xFFFFu) ? wa.x : 0.f;  acc += (h.x >> 16) ? wa.y : 0.f;
        acc += (h.y & 0xFFFFu) ? wa.z : 0.f;  acc += (h.y >> 16) ? wa.w : 0.f;
        acc += (h.z & 0xFFFFu) ? wb.x : 0.f;  acc += (h.z >> 16) ? wb.y : 0.f;
        acc += (h.w & 0xFFFFu) ? wb.z : 0.f;  acc += (h.w >> 16) ? wb.w : 0.f;
    }
#pragma unroll
    for (int off = 32; off; off >>= 1) acc += __shfl_down(acc, off);
    if (lane == 0) degv[row] = acc;
}

// t2T[f,e] = f2b(wde[e] * sum_{s<8} P[s][e][f])
__global__ void t2t_kernel(const u16* __restrict__ P, const float* __restrict__ wde,
                           u16* __restrict__ t2T) {
    __shared__ float tile[32][33];
    int tx = threadIdx.x, ty = threadIdx.y;
    int f0 = blockIdx.x * 32, e0 = blockIdx.y * 32;
#pragma unroll
    for (int i = 0; i < 4; i++) {
        int e = e0 + ty + i * 8;
        size_t idx = (size_t)e * 512 + f0 + tx;
        float s = 0.f;
#pragma unroll
        for (int sl = 0; sl < 8; sl++)
            s += b2f(P[idx + (size_t)sl * N_EDGES * 512]);
        tile[ty + i * 8][tx] = wde[e] * s;
    }
    __syncthreads();
#pragma unroll
    for (int i = 0; i < 4; i++)
        t2T[(size_t)(f0 + ty + i * 8) * N_EDGES + e0 + tx] = f2b(tile[tx][ty + i * 8]);
}

// out[n,f] = degv[n]*sum_{s<4} P[s][n][f] + bias[f]
__global__ __launch_bounds__(256) void final_kernel(const u16* __restrict__ P,
                                                    const float* __restrict__ degv,
                                                    const float* __restrict__ bias,
                                                    float* __restrict__ out) {
    int i8 = blockIdx.x * 256 + threadIdx.x;
    int base = i8 * 8;
    int n = base >> 9, f = base & 511;
    float s[8] = {0.f, 0.f, 0.f, 0.f, 0.f, 0.f, 0.f, 0.f};
#pragma unroll
    for (int sl = 0; sl < 4; sl++) {
        uint4 v = *(const uint4*)(P + (size_t)sl * N_NODES * 512 + base);
        u32 ws[4] = {v.x, v.y, v.z, v.w};
#pragma unroll
        for (int j = 0; j < 4; j++) {
            s[2 * j]     += b2f((u16)(ws[j] & 0xFFFFu));
            s[2 * j + 1] += b2f((u16)(ws[j] >> 16));
        }
    }
    float dv = degv[n];
    float4 o0, o1;
    o0.x = dv * s[0] + bias[f + 0]; o0.y = dv * s[1] + bias[f + 1];
    o0.z = dv * s[2] + bias[f + 2]; o0.w = dv * s[3] + bias[f + 3];
    o1.x = dv * s[4] + bias[f + 4]; o1.y = dv * s[5] + bias[f + 5];
    o1.z = dv * s[6] + bias[f + 6]; o1.w = dv * s[7] + bias[f + 7];
    *(float4*)(out + base) = o0;
    *(float4*)(out + base + 4) = o1;
}

// ---------------- MFMA GEMM: TBK=64, full-DMA + rotate-by-row swizzle ----------------
// Tile (MT*32) x (NT*32), 4 waves (2x2). bf16 row-major operands, k-contiguous.
// EPI 0: bf16 partial store at Cp + z*Ssz, ldc-row-major
// EPI 1: bf16 store C[m*ldc+n] scaled by degv[n]

#define TBK 64

template <int MT, int NT, int EPI>
__global__ __launch_bounds__(256, 4)
void gemm9(const u16* __restrict__ Ap, const u16* __restrict__ Bp,
           void* __restrict__ Cp, const float* __restrict__ degv,
           int KC, int lda, int ldb, int ldc, size_t Ssz) {
    __shared__ __align__(16) u16 Alds[MT * 32 * TBK];
    __shared__ __align__(16) u16 Blds[NT * 32 * TBK];
    const int t = threadIdx.x;
    const int m0 = blockIdx.x * (MT * 32), n0 = blockIdx.y * (NT * 32);
    const int kbase = blockIdx.z * KC;
    const int wave = t >> 6, lane = t & 63, quad = lane >> 4, lo = lane & 15;
    const int wm = (wave >> 1) * (MT * 16), wn = (wave & 1) * (NT * 16);

    f32x4 acc[MT][NT];
#pragma unroll
    for (int a = 0; a < MT; a++)
#pragma unroll
        for (int b = 0; b < NT; b++) acc[a][b] = (f32x4){0.f, 0.f, 0.f, 0.f};

    for (int kk = 0; kk < KC; kk += TBK) {
        const int k0 = kbase + kk;
        __syncthreads();
#pragma unroll
        for (int i = 0; i < MT; i++) {            // A: MT*32 rows x 8 chunks
            int c = t + i * 256;
            int r = c >> 3;
            int j = ((c & 7) - r) & 7;
            const u16* g = Ap + (size_t)(m0 + r) * lda + k0 + j * 8;
            __builtin_amdgcn_global_load_lds((const u32*)g, (u32*)(Alds + c * 8), 16, 0, 0);
        }
#pragma unroll
        for (int i = 0; i < NT; i++) {            // B: NT*32 rows x 8 chunks
            int c = t + i * 256;
            int r = c >> 3;
            int j = ((c & 7) - r) & 7;
            const u16* g = Bp + (size_t)(n0 + r) * ldb + k0 + j * 8;
            __builtin_amdgcn_global_load_lds((const u32*)g, (u32*)(Blds + c * 8), 16, 0, 0);
        }
        __syncthreads();

#pragma unroll
        for (int s2 = 0; s2 < 2; s2++) {
            bf16x8 af[MT], bfr[NT];
#pragma unroll
            for (int mt = 0; mt < MT; mt++) {
                int m = wm + mt * 16 + lo;
                int s = (s2 * 4 + quad + m) & 7;
                af[mt] = *(const bf16x8*)&Alds[m * TBK + s * 8];
            }
#pragma unroll
            for (int nt = 0; nt < NT; nt++) {
                int n = wn + nt * 16 + lo;
                int s = (s2 * 4 + quad + n) & 7;
                bfr[nt] = *(const bf16x8*)&Blds[n * TBK + s * 8];
            }
#pragma unroll
            for (int mt = 0; mt < MT; mt++)
#pragma unroll
                for (int nt = 0; nt < NT; nt++)
                    acc[mt][nt] = __builtin_amdgcn_mfma_f32_16x16x32_bf16(af[mt], bfr[nt], acc[mt][nt], 0, 0, 0);
        }
    }

    // epilogue: D[row=quad*4+i][col=lo] per 16x16 tile
    if (EPI == 0) {
        u16* C = (u16*)Cp + (size_t)blockIdx.z * Ssz;
#pragma unroll
        for (int mt = 0; mt < MT; mt++) {
            int rb = m0 + wm + mt * 16 + quad * 4;
#pragma unroll
            for (int i = 0; i < 4; i++)
#pragma unroll
                for (int nt = 0; nt < NT; nt++)
                    C[(size_t)(rb + i) * ldc + n0 + wn + nt * 16 + lo] = f2b(acc[mt][nt][i]);
        }
    } else {
        u16* C = (u16*)Cp;
        float dv[NT];
#pragma unroll
        for (int nt = 0; nt < NT; nt++) dv[nt] = degv[n0 + wn + nt * 16 + lo];
#pragma unroll
        for (int mt = 0; mt < MT; mt++) {
            int rb = m0 + wm + mt * 16 + quad * 4;
#pragma unroll
            for (int i = 0; i < 4; i++)
#pragma unroll
                for (int nt = 0; nt < NT; nt++)
                    C[(size_t)(rb + i) * ldc + n0 + wn + nt * 16 + lo] =
                        f2b(acc[mt][nt][i] * dv[nt]);
        }
    }
}

// ---------------- launch ----------------

extern "C" void kernel_launch(void* const* d_in, const int* in_sizes, int n_in,
                              void* d_out, int out_size, void* d_ws, size_t ws_size,
                              hipStream_t stream) {
    const float* x    = (const float*)d_in[0];
    const float* H    = (const float*)d_in[1];
    const float* W    = (const float*)d_in[2];
    const float* V    = (const float*)d_in[3];
    const float* bias = (const float*)d_in[4];
    float* out  = (float*)d_out;                       // (N, FT)
    float* wout = out + (size_t)N_NODES * FT;          // (E,)
    (void)in_sizes; (void)n_in; (void)out_size; (void)ws_size;

    char* wsb = (char*)d_ws;
    float* wsf   = (float*)d_ws;
    float* xv    = wsf;               // 8192 f
    float* zsum  = wsf + 8192;        // 4096 f  ┐ zeroed together (8192 f)
    float* desum = wsf + 12288;       // 4096 f  ┘
    float* degv  = wsf + 16384;       // 8192 f  (written directly)
    float* wde   = wsf + 24576;       // 4096 f -> 114,688 B
    u16*   Hbf   = (u16*)(wsb + 114688);                 // 64 MB  -> 67,223,552
    u16*   HTbf  = (u16*)(wsb + 67223552);               // 64 MB  -> 134,332,416
    u16*   WT    = (u16*)(wsb + 134332416);              // 0.5 MB -> 134,856,704
    u16*   doutT = (u16*)(wsb + 134856704);              // 8 MB   -> 143,245,312
    u16*   t2T   = (u16*)(wsb + 143245312);              // 4 MB   -> 147,439,616
    u16*   xb    = (u16*)(wsb + 147439616);              // 8 MB   -> 155,828,224
    u16*   P     = (u16*)(wsb + 155828224);              // 32 MB  -> 189,382,656

    // scalar path (zero folded into xv_xb; sigmoid+wt merged)
    xv_xb_kernel<<<N_NODES / 4, 256, 0, stream>>>(x, V, xv, xb, zsum);
    prep_h5_kernel<<<dim3(N_EDGES / 128, N_NODES / 128), 256, 0, stream>>>(
        H, xv, Hbf, HTbf, zsum, desum);
    sigwt_kernel<<<16 + 256, 256, 0, stream>>>(zsum, desum, wout, wde, W, WT);
    degv_kernel<<<N_NODES / 4, 256, 0, stream>>>(Hbf, wout, degv);

    // G1: doutT[f,n] = degv[n] * sum_fi WT[f,fi]*xb[n,fi]  (M=512, N=8192, K=512) 64x128 tile
    gemm9<2, 4, 1><<<dim3(FT / 64, N_NODES / 128, 1), 256, 0, stream>>>(
        WT, xb, doutT, degv, FT, FT, FT, N_NODES, 0);

    // G2: P[z][e][f] = partial sum_n HTbf[e,n]*doutT[f,n]  (M=4096, N=512, K=8192, S=8)
    gemm9<4, 4, 0><<<dim3(N_EDGES / 128, FT / 128, 8), 256, 0, stream>>>(
        HTbf, doutT, P, nullptr, N_NODES / 8, N_NODES, N_NODES, 512, (size_t)N_EDGES * 512);

    // t2T[f,e] = wde[e] * sum_s P
    t2t_kernel<<<dim3(FT / 32, N_EDGES / 32), dim3(32, 8), 0, stream>>>(P, wde, t2T);

    // G3: P[z][n][f] = partial sum_e Hbf[n,e]*t2T[f,e]   (M=8192, N=512, K=4096, S=4)
    gemm9<4, 4, 0><<<dim3(N_NODES / 128, FT / 128, 4), 256, 0, stream>>>(
        Hbf, t2T, P, nullptr, N_EDGES / 4, N_EDGES, N_EDGES, 512, (size_t)N_NODES * 512);

    // out = degv ⊙ (sum_s P) + bias
    final_kernel<<<(N_NODES * FT / 8) / 256, 256, 0, stream>>>(P, degv, bias, out);
}